// Round 1
// baseline (14873.895 us; speedup 1.0000x reference)
//
#include <hip/hip_runtime.h>
#include <math.h>

#define T 16384

__device__ __forceinline__ float bcast_f(float v, int lane) {
    return __int_as_float(__builtin_amdgcn_readlane(__float_as_int(v), lane));
}
__device__ __forceinline__ float sigm(float x) { return 1.0f / (1.0f + __expf(-x)); }
__device__ __forceinline__ float tanh_f(float x) { return 1.0f - 2.0f / (__expf(2.0f * x) + 1.0f); }

// ---------------------------------------------------------------------------
// Scan: build compacted per-type row indices.
// List order: l0 = p (type==1), l1 = c (type==0), l2 = s (type==2)
// meta[0..2] = counts per l, meta[3..5] = base row per l
// ---------------------------------------------------------------------------
__global__ void scan_types(const int* __restrict__ seq_types, int* __restrict__ rowidx,
                           int* __restrict__ meta) {
    __shared__ int cnt[256][3];
    __shared__ int pre[256][3];
    __shared__ int baseT[3];  // base indexed by TYPE
    int tid = threadIdx.x;
    int c0 = 0, c1 = 0, c2 = 0;
    for (int u = 0; u < 64; u++) {
        int ty = seq_types[tid * 64 + u];
        c0 += (ty == 0); c1 += (ty == 1); c2 += (ty == 2);
    }
    cnt[tid][0] = c0; cnt[tid][1] = c1; cnt[tid][2] = c2;
    __syncthreads();
    if (tid == 0) {
        int s0 = 0, s1 = 0, s2 = 0;
        for (int i = 0; i < 256; i++) {
            pre[i][0] = s0; pre[i][1] = s1; pre[i][2] = s2;
            s0 += cnt[i][0]; s1 += cnt[i][1]; s2 += cnt[i][2];
        }
        int base_l0 = 0, base_l1 = s1, base_l2 = s1 + s0;
        baseT[1] = base_l0;  // p
        baseT[0] = base_l1;  // c
        baseT[2] = base_l2;  // s
        meta[0] = s1; meta[1] = s0; meta[2] = s2;
        meta[3] = base_l0; meta[4] = base_l1; meta[5] = base_l2;
    }
    __syncthreads();
    int r0 = pre[tid][0], r1 = pre[tid][1], r2 = pre[tid][2];
    for (int u = 0; u < 64; u++) {
        int t = tid * 64 + u;
        int ty = seq_types[t];
        int rank = (ty == 0) ? r0++ : (ty == 1) ? r1++ : r2++;
        rowidx[t] = baseT[ty] + rank;
    }
}

// ---------------------------------------------------------------------------
// Phase A: per-t embedding gather + typed projection + time-LSTM input gates.
// Gx[t][g] = bih[g]+bhh[g] + sum_u Wih[g][u] * xs[t][u],  xs = [dwell, proj(9)]
// ---------------------------------------------------------------------------
__global__ void phaseA(const int* __restrict__ seq_items, const int* __restrict__ seq_types,
                       const float* __restrict__ dwell, const float* __restrict__ item_emb,
                       const float* __restrict__ click_proj, const float* __restrict__ purchase_proj,
                       const float* __restrict__ skip_proj, const float* __restrict__ Wih,
                       const float* __restrict__ bih, const float* __restrict__ bhh,
                       float* __restrict__ Gx) {
    int t = blockIdx.x;
    int lane = threadIdx.x;
    __shared__ float e[32];
    __shared__ float xs[10];
    int item = seq_items[t];
    if (lane < 32) e[lane] = item_emb[lane * 1000 + item];
    if (lane == 32) xs[0] = dwell[t];
    __syncthreads();
    int ty = seq_types[t];
    const float* P = (ty == 0) ? click_proj : (ty == 1) ? purchase_proj : skip_proj;
    if (lane < 9) {
        float s = 0.f;
        #pragma unroll
        for (int j = 0; j < 32; j++) s += P[lane * 32 + j] * e[j];
        xs[1 + lane] = s;
    }
    __syncthreads();
    #pragma unroll
    for (int g0 = 0; g0 < 128; g0 += 64) {
        int g = g0 + lane;
        float s = bih[g] + bhh[g];
        #pragma unroll
        for (int u = 0; u < 10; u++) s += Wih[g * 10 + u] * xs[u];
        Gx[t * 128 + g] = s;
    }
}

// ---------------------------------------------------------------------------
// Phase B: serial time-LSTM, 1 wave. Lane k owns hidden unit k (k<32),
// holds all 4 Whh rows (128 VGPRs). h broadcast via v_readlane -> SGPR fmac.
// ---------------------------------------------------------------------------
__global__ void __launch_bounds__(64, 1)
time_lstm(const float* __restrict__ Gx, const float* __restrict__ Whh, float* __restrict__ ys) {
    int k = threadIdx.x;
    int kk = (k < 32) ? k : 0;
    float Wi[32], Wf[32], Wg[32], Wo[32];
    #pragma unroll
    for (int j = 0; j < 32; j++) {
        Wi[j] = Whh[kk * 32 + j];
        Wf[j] = Whh[(32 + kk) * 32 + j];
        Wg[j] = Whh[(64 + kk) * 32 + j];
        Wo[j] = Whh[(96 + kk) * 32 + j];
    }
    float h = 0.f, c = 0.f;
    // 2-deep register prefetch of Gx rows (rows T, T+1 overrun into ys region: allocated, unused)
    float pri[2], prf[2], prg[2], pro[2];
    #pragma unroll
    for (int s = 0; s < 2; s++) {
        const float* g0 = Gx + s * 128 + kk;
        pri[s] = g0[0]; prf[s] = g0[32]; prg[s] = g0[64]; pro[s] = g0[96];
    }
    for (int t = 0; t < T; t++) {
        int sl = t & 1;
        float gi = pri[sl], gf = prf[sl], gg = prg[sl], go = pro[sl];
        const float* gn = Gx + (t + 2) * 128 + kk;
        pri[sl] = gn[0]; prf[sl] = gn[32]; prg[sl] = gn[64]; pro[sl] = gn[96];
        #pragma unroll
        for (int j = 0; j < 32; j++) {
            float hj = bcast_f(h, j);
            gi += Wi[j] * hj; gf += Wf[j] * hj; gg += Wg[j] * hj; go += Wo[j] * hj;
        }
        float iv = sigm(gi), fv = sigm(gf), gv = tanh_f(gg), ov = sigm(go);
        c = fv * c + iv * gv;
        h = ov * tanh_f(c);
        if (k < 32) ys[t * 32 + k] = h;
    }
}

// ---------------------------------------------------------------------------
// Phase C: S-LSTM input gates for all t, written compacted by type.
// Gs[rowidx[t]][j] = b[j] + sum_u Wih_l[j][u] * ys[t][u]
// ---------------------------------------------------------------------------
__global__ void phaseC(const float* __restrict__ ys, const int* __restrict__ seq_types,
                       const int* __restrict__ rowidx,
                       const float* __restrict__ pW, const float* __restrict__ pbi, const float* __restrict__ pbh,
                       const float* __restrict__ cW, const float* __restrict__ cbi, const float* __restrict__ cbh,
                       const float* __restrict__ sW, const float* __restrict__ sbi, const float* __restrict__ sbh,
                       float* __restrict__ Gs) {
    int t = blockIdx.x;
    int lane = threadIdx.x;
    __shared__ float y[32];
    if (lane < 32) y[lane] = ys[t * 32 + lane];
    __syncthreads();
    int ty = seq_types[t];
    const float* W; const float* bi; const float* bh;
    if (ty == 1)      { W = pW; bi = pbi; bh = pbh; }
    else if (ty == 0) { W = cW; bi = cbi; bh = cbh; }
    else              { W = sW; bi = sbi; bh = sbh; }
    float* out = Gs + (size_t)rowidx[t] * 160;
    for (int j = lane; j < 160; j += 64) {
        float s = bi[j] + bh[j];
        #pragma unroll
        for (int u = 0; u < 32; u++) s += W[j * 32 + u] * y[u];
        out[j] = s;
    }
}

// ---------------------------------------------------------------------------
// Phase D: 3 independent serial S-LSTMs over compacted lists (1 wave each).
// Lane k owns hidden unit k (k<40); 160 Whh VGPRs/lane.
// ---------------------------------------------------------------------------
__global__ void __launch_bounds__(64, 1)
s_lstm(const float* __restrict__ Gs, const int* __restrict__ meta,
       const float* __restrict__ pWhh, const float* __restrict__ cWhh, const float* __restrict__ sWhh,
       float* __restrict__ H) {
    int l = blockIdx.x;
    const float* Whh = (l == 0) ? pWhh : (l == 1) ? cWhh : sWhh;
    int count = meta[l];
    int base = meta[3 + l];
    int k = threadIdx.x;
    int kk = (k < 40) ? k : 0;
    float Wi[40], Wf[40], Wg[40], Wo[40];
    #pragma unroll
    for (int j = 0; j < 40; j++) {
        Wi[j] = Whh[kk * 40 + j];
        Wf[j] = Whh[(40 + kk) * 40 + j];
        Wg[j] = Whh[(80 + kk) * 40 + j];
        Wo[j] = Whh[(120 + kk) * 40 + j];
    }
    float h = 0.f, c = 0.f;
    const float* G = Gs + (size_t)base * 160 + kk;
    float pri[2], prf[2], prg[2], pro[2];
    #pragma unroll
    for (int s = 0; s < 2; s++) {
        const float* g0 = G + s * 160;
        pri[s] = g0[0]; prf[s] = g0[40]; prg[s] = g0[80]; pro[s] = g0[120];
    }
    for (int t = 0; t < count; t++) {
        int sl = t & 1;
        float gi = pri[sl], gf = prf[sl], gg = prg[sl], go = pro[sl];
        const float* gn = G + (t + 2) * 160;  // overrun reads stay inside d_ws
        pri[sl] = gn[0]; prf[sl] = gn[40]; prg[sl] = gn[80]; pro[sl] = gn[120];
        #pragma unroll
        for (int j = 0; j < 40; j++) {
            float hj = bcast_f(h, j);
            gi += Wi[j] * hj; gf += Wf[j] * hj; gg += Wg[j] * hj; go += Wo[j] * hj;
        }
        float iv = sigm(gi), fv = sigm(gf), gv = tanh_f(gg), ov = sigm(go);
        c = fv * c + iv * gv;
        h = ov * tanh_f(c);
    }
    if (k < 40) H[l * 40 + k] = h;
}

// ---------------------------------------------------------------------------
// Phase E: fusion vector (216) + 16-unit ReLU MLP + scalar head.
// fusion = [next_e(32), user_e(32), H_r(32), H_s(40), H_c(40), H_p(40)]
// ---------------------------------------------------------------------------
__global__ void phaseE(const int* __restrict__ user, const int* __restrict__ nextitem,
                       const float* __restrict__ item_emb, const float* __restrict__ user_emb,
                       const float* __restrict__ ys, const float* __restrict__ H,
                       const float* __restrict__ W1, const float* __restrict__ b1,
                       const float* __restrict__ W2, const float* __restrict__ b2,
                       float* __restrict__ out) {
    __shared__ float f[216];
    __shared__ float hid[16];
    int tid = threadIdx.x;
    if (tid < 32)       f[tid] = item_emb[tid * 1000 + nextitem[0]];
    else if (tid < 64)  f[tid] = user_emb[(tid - 32) * 1000 + user[0]];
    else if (tid < 96)  f[tid] = ys[(size_t)(T - 1) * 32 + (tid - 64)];
    else if (tid < 136) f[tid] = H[2 * 40 + (tid - 96)];    // H_s
    else if (tid < 176) f[tid] = H[1 * 40 + (tid - 136)];   // H_c
    else if (tid < 216) f[tid] = H[0 * 40 + (tid - 176)];   // H_p
    __syncthreads();
    if (tid < 16) {
        float s = b1[tid];
        for (int u = 0; u < 216; u++) s += W1[tid * 216 + u] * f[u];
        hid[tid] = fmaxf(s, 0.f);
    }
    __syncthreads();
    if (tid == 0) {
        float s = b2[0];
        #pragma unroll
        for (int m = 0; m < 16; m++) s += W2[m] * hid[m];
        out[0] = s;
    }
}

extern "C" void kernel_launch(void* const* d_in, const int* in_sizes, int n_in,
                              void* d_out, int out_size, void* d_ws, size_t ws_size,
                              hipStream_t stream) {
    const int*   user      = (const int*)d_in[0];
    const int*   nextitem  = (const int*)d_in[1];
    const int*   seq_items = (const int*)d_in[2];
    const int*   seq_types = (const int*)d_in[3];
    const float* dwell     = (const float*)d_in[4];
    const float* item_emb  = (const float*)d_in[5];
    const float* user_emb  = (const float*)d_in[6];
    const float* click     = (const float*)d_in[7];
    const float* purch     = (const float*)d_in[8];
    const float* skip      = (const float*)d_in[9];
    const float* tWih = (const float*)d_in[10];
    const float* tWhh = (const float*)d_in[11];
    const float* tbih = (const float*)d_in[12];
    const float* tbhh = (const float*)d_in[13];
    const float* pWih = (const float*)d_in[14], *pWhh = (const float*)d_in[15];
    const float* pbih = (const float*)d_in[16], *pbhh = (const float*)d_in[17];
    const float* cWih = (const float*)d_in[18], *cWhh = (const float*)d_in[19];
    const float* cbih = (const float*)d_in[20], *cbhh = (const float*)d_in[21];
    const float* sWih = (const float*)d_in[22], *sWhh = (const float*)d_in[23];
    const float* sbih = (const float*)d_in[24], *sbhh = (const float*)d_in[25];
    const float* W1 = (const float*)d_in[26], *b1 = (const float*)d_in[27];
    const float* W2 = (const float*)d_in[28], *b2 = (const float*)d_in[29];

    float* ws  = (float*)d_ws;
    float* Gx  = ws;                        // T*128 floats
    float* ysb = Gx + (size_t)T * 128;      // T*32
    float* Gs  = ysb + (size_t)T * 32;      // T*160 (compacted)
    float* H   = Gs + (size_t)T * 160;      // 128 (120 used)
    int*   meta   = (int*)(H + 128);        // 8 (6 used)
    int*   rowidx = meta + 8;               // T

    scan_types<<<1, 256, 0, stream>>>(seq_types, rowidx, meta);
    phaseA<<<T, 64, 0, stream>>>(seq_items, seq_types, dwell, item_emb, click, purch, skip,
                                 tWih, tbih, tbhh, Gx);
    time_lstm<<<1, 64, 0, stream>>>(Gx, tWhh, ysb);
    phaseC<<<T, 64, 0, stream>>>(ysb, seq_types, rowidx,
                                 pWih, pbih, pbhh, cWih, cbih, cbhh, sWih, sbih, sbhh, Gs);
    s_lstm<<<3, 64, 0, stream>>>(Gs, meta, pWhh, cWhh, sWhh, H);
    phaseE<<<1, 256, 0, stream>>>(user, nextitem, item_emb, user_emb, ysb, H,
                                  W1, b1, W2, b2, (float*)d_out);
}

// Round 2
// 10652.309 us; speedup vs baseline: 1.3963x; 1.3963x over previous
//
#include <hip/hip_runtime.h>
#include <math.h>

#define T 16384

__device__ __forceinline__ float bcast_f(float v, int lane) {
    return __int_as_float(__builtin_amdgcn_readlane(__float_as_int(v), lane));
}
__device__ __forceinline__ float sigm(float x) { return 1.0f / (1.0f + __expf(-x)); }

// ---------------------------------------------------------------------------
// Scan: build compacted per-type row indices.
// List order: l0 = p (type==1), l1 = c (type==0), l2 = s (type==2)
// meta[0..2] = counts per l, meta[3..5] = base row per l
// ---------------------------------------------------------------------------
__global__ void scan_types(const int* __restrict__ seq_types, int* __restrict__ rowidx,
                           int* __restrict__ meta) {
    __shared__ int cnt[256][3];
    __shared__ int pre[256][3];
    __shared__ int baseT[3];  // base indexed by TYPE
    int tid = threadIdx.x;
    int c0 = 0, c1 = 0, c2 = 0;
    for (int u = 0; u < 64; u++) {
        int ty = seq_types[tid * 64 + u];
        c0 += (ty == 0); c1 += (ty == 1); c2 += (ty == 2);
    }
    cnt[tid][0] = c0; cnt[tid][1] = c1; cnt[tid][2] = c2;
    __syncthreads();
    if (tid == 0) {
        int s0 = 0, s1 = 0, s2 = 0;
        for (int i = 0; i < 256; i++) {
            pre[i][0] = s0; pre[i][1] = s1; pre[i][2] = s2;
            s0 += cnt[i][0]; s1 += cnt[i][1]; s2 += cnt[i][2];
        }
        int base_l0 = 0, base_l1 = s1, base_l2 = s1 + s0;
        baseT[1] = base_l0;  // p
        baseT[0] = base_l1;  // c
        baseT[2] = base_l2;  // s
        meta[0] = s1; meta[1] = s0; meta[2] = s2;
        meta[3] = base_l0; meta[4] = base_l1; meta[5] = base_l2;
    }
    __syncthreads();
    int r0 = pre[tid][0], r1 = pre[tid][1], r2 = pre[tid][2];
    for (int u = 0; u < 64; u++) {
        int t = tid * 64 + u;
        int ty = seq_types[t];
        int rank = (ty == 0) ? r0++ : (ty == 1) ? r1++ : r2++;
        rowidx[t] = baseT[ty] + rank;
    }
}

// ---------------------------------------------------------------------------
// Phase A: per-t embedding gather + typed projection + time-LSTM input gates.
// ---------------------------------------------------------------------------
__global__ void phaseA(const int* __restrict__ seq_items, const int* __restrict__ seq_types,
                       const float* __restrict__ dwell, const float* __restrict__ item_emb,
                       const float* __restrict__ click_proj, const float* __restrict__ purchase_proj,
                       const float* __restrict__ skip_proj, const float* __restrict__ Wih,
                       const float* __restrict__ bih, const float* __restrict__ bhh,
                       float* __restrict__ Gx) {
    int t = blockIdx.x;
    int lane = threadIdx.x;
    __shared__ float e[32];
    __shared__ float xs[10];
    int item = seq_items[t];
    if (lane < 32) e[lane] = item_emb[lane * 1000 + item];
    if (lane == 32) xs[0] = dwell[t];
    __syncthreads();
    int ty = seq_types[t];
    const float* P = (ty == 0) ? click_proj : (ty == 1) ? purchase_proj : skip_proj;
    if (lane < 9) {
        float s = 0.f;
        #pragma unroll
        for (int j = 0; j < 32; j++) s += P[lane * 32 + j] * e[j];
        xs[1 + lane] = s;
    }
    __syncthreads();
    #pragma unroll
    for (int g0 = 0; g0 < 128; g0 += 64) {
        int g = g0 + lane;
        float s = bih[g] + bhh[g];
        #pragma unroll
        for (int u = 0; u < 10; u++) s += Wih[g * 10 + u] * xs[u];
        Gx[t * 128 + g] = s;
    }
}

// ---------------------------------------------------------------------------
// Phase B: serial time-LSTM, 1 wave, gate-split over 64 lanes.
// Lane L owns matrix rows L and L+64:
//   rows 0..31 = i, 32..63 = f, 64..95 = g, 96..127 = o
//   low lanes (L<32):  rA = i_k, rB = g_k (tanh)
//   high lanes (L>=32): rA = f_k, rB = o_k
// Both halves redundantly maintain (c,h) for unit k = L&31 so readlane
// broadcasts of h work from lanes 0..31.
// ---------------------------------------------------------------------------
__global__ void __attribute__((amdgpu_flat_work_group_size(64, 64), amdgpu_waves_per_eu(1, 1)))
time_lstm(const float* __restrict__ Gx, const float* __restrict__ Whh, float* __restrict__ ys) {
    int L = threadIdx.x;
    bool isLow = (L < 32);
    int unit = L & 31;
    float WA[32], WB[32];
    #pragma unroll
    for (int j = 0; j < 32; j++) {
        WA[j] = Whh[L * 32 + j];
        WB[j] = Whh[(L + 64) * 32 + j];
    }
    int paddr = (L ^ 32) << 2;                 // ds_bpermute byte addr of partner lane
    float mB = isLow ? 2.0f : 1.0f;            // tanh(x) = 2*sigm(2x)-1 on low lanes
    float c = 0.f, h = 0.f;
    const float* GA = Gx + L;
    const float* GB = Gx + 64 + L;
    float pA[4], pB[4];
    #pragma unroll
    for (int u = 0; u < 4; u++) { pA[u] = GA[u * 128]; pB[u] = GB[u * 128]; }
    for (int t = 0; t < T; t += 4) {
        #pragma unroll
        for (int u = 0; u < 4; u++) {
            float gA = pA[u], gB = pB[u];
            // prefetch 4 steps ahead (overrun rows T..T+7 land in ys region: allocated)
            pA[u] = GA[(t + u + 4) * 128];
            pB[u] = GB[(t + u + 4) * 128];
            #pragma unroll
            for (int j = 0; j < 32; j++) {
                float hj = bcast_f(h, j);
                gA = __builtin_fmaf(WA[j], hj, gA);
                gB = __builtin_fmaf(WB[j], hj, gB);
            }
            float a1 = sigm(gA);                           // i (low) / f (high)
            float u2 = sigm(gB * mB);
            float a2 = isLow ? 2.f * u2 - 1.f : u2;        // g (low) / o (high)
            float p  = a1 * a2;                            // i*g (meaningful on low)
            float x1 = __int_as_float(__builtin_amdgcn_ds_bpermute(
                           paddr, __float_as_int(isLow ? p : a1)));
            float x2 = __int_as_float(__builtin_amdgcn_ds_bpermute(
                           paddr, __float_as_int(a2)));
            float fv = isLow ? x1 : a1;
            float pv = isLow ? p  : x1;
            float ov = isLow ? x2 : a2;
            c = __builtin_fmaf(fv, c, pv);
            float tc = 2.f * sigm(2.f * c) - 1.f;          // tanh(c)
            h = ov * tc;
            if (isLow) ys[(t + u) * 32 + unit] = h;
        }
    }
}

// ---------------------------------------------------------------------------
// Phase C: S-LSTM input gates for all t, written compacted by type.
// ---------------------------------------------------------------------------
__global__ void phaseC(const float* __restrict__ ys, const int* __restrict__ seq_types,
                       const int* __restrict__ rowidx,
                       const float* __restrict__ pW, const float* __restrict__ pbi, const float* __restrict__ pbh,
                       const float* __restrict__ cW, const float* __restrict__ cbi, const float* __restrict__ cbh,
                       const float* __restrict__ sW, const float* __restrict__ sbi, const float* __restrict__ sbh,
                       float* __restrict__ Gs) {
    int t = blockIdx.x;
    int lane = threadIdx.x;
    __shared__ float y[32];
    if (lane < 32) y[lane] = ys[t * 32 + lane];
    __syncthreads();
    int ty = seq_types[t];
    const float* W; const float* bi; const float* bh;
    if (ty == 1)      { W = pW; bi = pbi; bh = pbh; }
    else if (ty == 0) { W = cW; bi = cbi; bh = cbh; }
    else              { W = sW; bi = sbi; bh = sbh; }
    float* out = Gs + (size_t)rowidx[t] * 160;
    for (int j = lane; j < 160; j += 64) {
        float s = bi[j] + bh[j];
        #pragma unroll
        for (int u = 0; u < 32; u++) s += W[j * 32 + u] * y[u];
        out[j] = s;
    }
}

// ---------------------------------------------------------------------------
// Phase D: 3 independent serial S-LSTMs over compacted lists (1 wave each).
// Lane k owns hidden unit k (k<40); 160 Whh floats/lane. Unroll x4 with
// named prefetch registers; tail steps masked (state frozen when t>=count).
// ---------------------------------------------------------------------------
__global__ void __attribute__((amdgpu_flat_work_group_size(64, 64), amdgpu_waves_per_eu(1, 1)))
s_lstm(const float* __restrict__ Gs, const int* __restrict__ meta,
       const float* __restrict__ pWhh, const float* __restrict__ cWhh, const float* __restrict__ sWhh,
       float* __restrict__ H) {
    int l = blockIdx.x;
    const float* Whh = (l == 0) ? pWhh : (l == 1) ? cWhh : sWhh;
    int count = meta[l];
    int base = meta[3 + l];
    int k = threadIdx.x;
    int kk = (k < 40) ? k : 0;
    float Wi[40], Wf[40], Wg[40], Wo[40];
    #pragma unroll
    for (int j = 0; j < 40; j++) {
        Wi[j] = Whh[kk * 40 + j];
        Wf[j] = Whh[(40 + kk) * 40 + j];
        Wg[j] = Whh[(80 + kk) * 40 + j];
        Wo[j] = Whh[(120 + kk) * 40 + j];
    }
    float h = 0.f, c = 0.f;
    const float* G = Gs + (size_t)base * 160 + kk;
    float pi[4], pf[4], pg[4], po[4];
    #pragma unroll
    for (int u = 0; u < 4; u++) {
        const float* g0 = G + u * 160;
        pi[u] = g0[0]; pf[u] = g0[40]; pg[u] = g0[80]; po[u] = g0[120];
    }
    int steps = (count + 3) & ~3;
    for (int t = 0; t < steps; t += 4) {
        #pragma unroll
        for (int u = 0; u < 4; u++) {
            float gi = pi[u], gf = pf[u], gg = pg[u], go = po[u];
            const float* gn = G + (t + u + 4) * 160;   // overrun stays inside d_ws
            pi[u] = gn[0]; pf[u] = gn[40]; pg[u] = gn[80]; po[u] = gn[120];
            #pragma unroll
            for (int j = 0; j < 40; j++) {
                float hj = bcast_f(h, j);
                gi = __builtin_fmaf(Wi[j], hj, gi);
                gf = __builtin_fmaf(Wf[j], hj, gf);
                gg = __builtin_fmaf(Wg[j], hj, gg);
                go = __builtin_fmaf(Wo[j], hj, go);
            }
            float iv = sigm(gi), fv = sigm(gf);
            float gv = 2.f * sigm(2.f * gg) - 1.f;     // tanh
            float ov = sigm(go);
            float cn = __builtin_fmaf(fv, c, iv * gv);
            float tc = 2.f * sigm(2.f * cn) - 1.f;     // tanh
            float hn = ov * tc;
            bool m = (t + u) < count;
            c = m ? cn : c;
            h = m ? hn : h;
        }
    }
    if (k < 40) H[l * 40 + k] = h;
}

// ---------------------------------------------------------------------------
// Phase E: fusion vector (216) + 16-unit ReLU MLP + scalar head.
// ---------------------------------------------------------------------------
__global__ void phaseE(const int* __restrict__ user, const int* __restrict__ nextitem,
                       const float* __restrict__ item_emb, const float* __restrict__ user_emb,
                       const float* __restrict__ ys, const float* __restrict__ H,
                       const float* __restrict__ W1, const float* __restrict__ b1,
                       const float* __restrict__ W2, const float* __restrict__ b2,
                       float* __restrict__ out) {
    __shared__ float f[216];
    __shared__ float hid[16];
    int tid = threadIdx.x;
    if (tid < 32)       f[tid] = item_emb[tid * 1000 + nextitem[0]];
    else if (tid < 64)  f[tid] = user_emb[(tid - 32) * 1000 + user[0]];
    else if (tid < 96)  f[tid] = ys[(size_t)(T - 1) * 32 + (tid - 64)];
    else if (tid < 136) f[tid] = H[2 * 40 + (tid - 96)];    // H_s
    else if (tid < 176) f[tid] = H[1 * 40 + (tid - 136)];   // H_c
    else if (tid < 216) f[tid] = H[0 * 40 + (tid - 176)];   // H_p
    __syncthreads();
    if (tid < 16) {
        float s = b1[tid];
        for (int u = 0; u < 216; u++) s += W1[tid * 216 + u] * f[u];
        hid[tid] = fmaxf(s, 0.f);
    }
    __syncthreads();
    if (tid == 0) {
        float s = b2[0];
        #pragma unroll
        for (int m = 0; m < 16; m++) s += W2[m] * hid[m];
        out[0] = s;
    }
}

extern "C" void kernel_launch(void* const* d_in, const int* in_sizes, int n_in,
                              void* d_out, int out_size, void* d_ws, size_t ws_size,
                              hipStream_t stream) {
    const int*   user      = (const int*)d_in[0];
    const int*   nextitem  = (const int*)d_in[1];
    const int*   seq_items = (const int*)d_in[2];
    const int*   seq_types = (const int*)d_in[3];
    const float* dwell     = (const float*)d_in[4];
    const float* item_emb  = (const float*)d_in[5];
    const float* user_emb  = (const float*)d_in[6];
    const float* click     = (const float*)d_in[7];
    const float* purch     = (const float*)d_in[8];
    const float* skip      = (const float*)d_in[9];
    const float* tWih = (const float*)d_in[10];
    const float* tWhh = (const float*)d_in[11];
    const float* tbih = (const float*)d_in[12];
    const float* tbhh = (const float*)d_in[13];
    const float* pWih = (const float*)d_in[14], *pWhh = (const float*)d_in[15];
    const float* pbih = (const float*)d_in[16], *pbhh = (const float*)d_in[17];
    const float* cWih = (const float*)d_in[18], *cWhh = (const float*)d_in[19];
    const float* cbih = (const float*)d_in[20], *cbhh = (const float*)d_in[21];
    const float* sWih = (const float*)d_in[22], *sWhh = (const float*)d_in[23];
    const float* sbih = (const float*)d_in[24], *sbhh = (const float*)d_in[25];
    const float* W1 = (const float*)d_in[26], *b1 = (const float*)d_in[27];
    const float* W2 = (const float*)d_in[28], *b2 = (const float*)d_in[29];

    float* ws  = (float*)d_ws;
    float* Gx  = ws;                        // T*128 floats
    float* ysb = Gx + (size_t)T * 128;      // T*32
    float* Gs  = ysb + (size_t)T * 32;      // T*160 (compacted)
    float* H   = Gs + (size_t)T * 160;      // 128 (120 used)
    int*   meta   = (int*)(H + 128);        // 8 (6 used)
    int*   rowidx = meta + 8;               // T

    scan_types<<<1, 256, 0, stream>>>(seq_types, rowidx, meta);
    phaseA<<<T, 64, 0, stream>>>(seq_items, seq_types, dwell, item_emb, click, purch, skip,
                                 tWih, tbih, tbhh, Gx);
    time_lstm<<<1, 64, 0, stream>>>(Gx, tWhh, ysb);
    phaseC<<<T, 64, 0, stream>>>(ysb, seq_types, rowidx,
                                 pWih, pbih, pbhh, cWih, cbih, cbhh, sWih, sbih, sbhh, Gs);
    s_lstm<<<3, 64, 0, stream>>>(Gs, meta, pWhh, cWhh, sWhh, H);
    phaseE<<<1, 256, 0, stream>>>(user, nextitem, item_emb, user_emb, ysb, H,
                                  W1, b1, W2, b2, (float*)d_out);
}

// Round 3
// 8464.896 us; speedup vs baseline: 1.7571x; 1.2584x over previous
//
#include <hip/hip_runtime.h>
#include <math.h>

#define T 16384

__device__ __forceinline__ float bcast_f(float v, int lane) {
    return __int_as_float(__builtin_amdgcn_readlane(__float_as_int(v), lane));
}
__device__ __forceinline__ float sigm(float x) { return 1.0f / (1.0f + __expf(-x)); }

// ---------------------------------------------------------------------------
// Heater: keeps the SMU seeing full-chip activity so clocks stay boosted
// while a single-wave serial kernel runs. Exits when *flag >= target.
// ---------------------------------------------------------------------------
__device__ __forceinline__ void heater_spin(const int* flag, int target, float* dummy) {
    float a = threadIdx.x * 0.001f + 1.0001f;
    float b = 0.99991f;
    float c0 = 0.f, c1 = 1.f, c2 = 2.f, c3 = 3.f;
    for (;;) {
        #pragma unroll
        for (int i = 0; i < 64; i++) {
            c0 = __builtin_fmaf(a, b, c0);
            c1 = __builtin_fmaf(a, b, c1);
            c2 = __builtin_fmaf(a, b, c2);
            c3 = __builtin_fmaf(a, b, c3);
        }
        if (__hip_atomic_load(flag, __ATOMIC_RELAXED, __HIP_MEMORY_SCOPE_AGENT) >= target) break;
    }
    float s = (c0 + c1) + (c2 + c3);
    if (s == 1234.56789f) dummy[0] = s;  // unprovable: blocks DCE, never executes
}

// ---------------------------------------------------------------------------
// Scan: build compacted per-type row indices.
// List order: l0 = p (type==1), l1 = c (type==0), l2 = s (type==2)
// meta[0..2] = counts per l, meta[3..5] = base row per l
// ---------------------------------------------------------------------------
__global__ void scan_types(const int* __restrict__ seq_types, int* __restrict__ rowidx,
                           int* __restrict__ meta) {
    __shared__ int cnt[256][3];
    __shared__ int pre[256][3];
    __shared__ int baseT[3];  // base indexed by TYPE
    int tid = threadIdx.x;
    int c0 = 0, c1 = 0, c2 = 0;
    for (int u = 0; u < 64; u++) {
        int ty = seq_types[tid * 64 + u];
        c0 += (ty == 0); c1 += (ty == 1); c2 += (ty == 2);
    }
    cnt[tid][0] = c0; cnt[tid][1] = c1; cnt[tid][2] = c2;
    __syncthreads();
    if (tid == 0) {
        int s0 = 0, s1 = 0, s2 = 0;
        for (int i = 0; i < 256; i++) {
            pre[i][0] = s0; pre[i][1] = s1; pre[i][2] = s2;
            s0 += cnt[i][0]; s1 += cnt[i][1]; s2 += cnt[i][2];
        }
        int base_l0 = 0, base_l1 = s1, base_l2 = s1 + s0;
        baseT[1] = base_l0;  // p
        baseT[0] = base_l1;  // c
        baseT[2] = base_l2;  // s
        meta[0] = s1; meta[1] = s0; meta[2] = s2;
        meta[3] = base_l0; meta[4] = base_l1; meta[5] = base_l2;
    }
    __syncthreads();
    int r0 = pre[tid][0], r1 = pre[tid][1], r2 = pre[tid][2];
    for (int u = 0; u < 64; u++) {
        int t = tid * 64 + u;
        int ty = seq_types[t];
        int rank = (ty == 0) ? r0++ : (ty == 1) ? r1++ : r2++;
        rowidx[t] = baseT[ty] + rank;
    }
}

// ---------------------------------------------------------------------------
// Phase A: per-t embedding gather + typed projection + time-LSTM input gates.
// ---------------------------------------------------------------------------
__global__ void phaseA(const int* __restrict__ seq_items, const int* __restrict__ seq_types,
                       const float* __restrict__ dwell, const float* __restrict__ item_emb,
                       const float* __restrict__ click_proj, const float* __restrict__ purchase_proj,
                       const float* __restrict__ skip_proj, const float* __restrict__ Wih,
                       const float* __restrict__ bih, const float* __restrict__ bhh,
                       float* __restrict__ Gx) {
    int t = blockIdx.x;
    int lane = threadIdx.x;
    __shared__ float e[32];
    __shared__ float xs[10];
    int item = seq_items[t];
    if (lane < 32) e[lane] = item_emb[lane * 1000 + item];
    if (lane == 32) xs[0] = dwell[t];
    __syncthreads();
    int ty = seq_types[t];
    const float* P = (ty == 0) ? click_proj : (ty == 1) ? purchase_proj : skip_proj;
    if (lane < 9) {
        float s = 0.f;
        #pragma unroll
        for (int j = 0; j < 32; j++) s += P[lane * 32 + j] * e[j];
        xs[1 + lane] = s;
    }
    __syncthreads();
    #pragma unroll
    for (int g0 = 0; g0 < 128; g0 += 64) {
        int g = g0 + lane;
        float s = bih[g] + bhh[g];
        #pragma unroll
        for (int u = 0; u < 10; u++) s += Wih[g * 10 + u] * xs[u];
        Gx[t * 128 + g] = s;
    }
}

// ---------------------------------------------------------------------------
// Phase B: serial time-LSTM, 1 real wave (block 0) + heater blocks.
// Gate-split over 64 lanes: lane L owns matrix rows L and L+64.
//   low lanes (L<32):  rA = i_k, rB = g_k (tanh)
//   high lanes (L>=32): rA = f_k, rB = o_k
// 4-way partial accumulators (dep chain 8 fmas), prefetch depth 8.
// ---------------------------------------------------------------------------
__global__ void __attribute__((amdgpu_flat_work_group_size(64, 64), amdgpu_waves_per_eu(1, 1)))
time_lstm(const float* __restrict__ Gx, const float* __restrict__ Whh, float* __restrict__ ys,
          int* __restrict__ flag) {
    if (blockIdx.x != 0) {
        heater_spin(flag, 1, (float*)(flag + 4));
        return;
    }
    int L = threadIdx.x;
    bool isLow = (L < 32);
    int unit = L & 31;
    float WA[32], WB[32];
    #pragma unroll
    for (int j = 0; j < 32; j++) {
        WA[j] = Whh[L * 32 + j];
        WB[j] = Whh[(L + 64) * 32 + j];
    }
    int paddr = (L ^ 32) << 2;                 // ds_bpermute byte addr of partner lane
    float mB = isLow ? 2.0f : 1.0f;            // tanh(x) = 2*sigm(2x)-1 on low lanes
    float c = 0.f, h = 0.f;
    const float* GA = Gx + L;
    const float* GB = Gx + 64 + L;
    float pA[8], pB[8];
    #pragma unroll
    for (int u = 0; u < 8; u++) { pA[u] = GA[u * 128]; pB[u] = GB[u * 128]; }
    for (int t = 0; t < T; t += 8) {
        #pragma unroll
        for (int u = 0; u < 8; u++) {
            float gxA = pA[u], gxB = pB[u];
            // prefetch 8 steps ahead (overrun rows T..T+15 land in ys region: allocated)
            pA[u] = GA[(t + u + 8) * 128];
            pB[u] = GB[(t + u + 8) * 128];
            float a0 = 0.f, a1 = 0.f, a2 = 0.f, a3 = 0.f;
            float b0 = 0.f, b1 = 0.f, b2 = 0.f, b3 = 0.f;
            #pragma unroll
            for (int j = 0; j < 32; j += 4) {
                float h0 = bcast_f(h, j);
                float h1 = bcast_f(h, j + 1);
                float h2 = bcast_f(h, j + 2);
                float h3 = bcast_f(h, j + 3);
                a0 = __builtin_fmaf(WA[j],     h0, a0);
                b0 = __builtin_fmaf(WB[j],     h0, b0);
                a1 = __builtin_fmaf(WA[j + 1], h1, a1);
                b1 = __builtin_fmaf(WB[j + 1], h1, b1);
                a2 = __builtin_fmaf(WA[j + 2], h2, a2);
                b2 = __builtin_fmaf(WB[j + 2], h2, b2);
                a3 = __builtin_fmaf(WA[j + 3], h3, a3);
                b3 = __builtin_fmaf(WB[j + 3], h3, b3);
            }
            float gA = ((a0 + a1) + (a2 + a3)) + gxA;
            float gB = ((b0 + b1) + (b2 + b3)) + gxB;
            float v1 = sigm(gA);                           // i (low) / f (high)
            float u2 = sigm(gB * mB);
            float v2 = isLow ? 2.f * u2 - 1.f : u2;        // g (low) / o (high)
            float p  = v1 * v2;                            // i*g (meaningful on low)
            float x1 = __int_as_float(__builtin_amdgcn_ds_bpermute(
                           paddr, __float_as_int(isLow ? p : v1)));
            float x2 = __int_as_float(__builtin_amdgcn_ds_bpermute(
                           paddr, __float_as_int(v2)));
            float fv = isLow ? x1 : v1;
            float pv = isLow ? p  : x1;
            float ov = isLow ? x2 : v2;
            c = __builtin_fmaf(fv, c, pv);
            float tc = 2.f * sigm(2.f * c) - 1.f;          // tanh(c)
            h = ov * tc;
            if (isLow) ys[(t + u) * 32 + unit] = h;
        }
    }
    if (L == 0) __hip_atomic_store(flag, 1, __ATOMIC_RELAXED, __HIP_MEMORY_SCOPE_AGENT);
}

// ---------------------------------------------------------------------------
// Phase C: S-LSTM input gates for all t, written compacted by type.
// ---------------------------------------------------------------------------
__global__ void phaseC(const float* __restrict__ ys, const int* __restrict__ seq_types,
                       const int* __restrict__ rowidx,
                       const float* __restrict__ pW, const float* __restrict__ pbi, const float* __restrict__ pbh,
                       const float* __restrict__ cW, const float* __restrict__ cbi, const float* __restrict__ cbh,
                       const float* __restrict__ sW, const float* __restrict__ sbi, const float* __restrict__ sbh,
                       float* __restrict__ Gs) {
    int t = blockIdx.x;
    int lane = threadIdx.x;
    __shared__ float y[32];
    if (lane < 32) y[lane] = ys[t * 32 + lane];
    __syncthreads();
    int ty = seq_types[t];
    const float* W; const float* bi; const float* bh;
    if (ty == 1)      { W = pW; bi = pbi; bh = pbh; }
    else if (ty == 0) { W = cW; bi = cbi; bh = cbh; }
    else              { W = sW; bi = sbi; bh = sbh; }
    float* out = Gs + (size_t)rowidx[t] * 160;
    for (int j = lane; j < 160; j += 64) {
        float s = bi[j] + bh[j];
        #pragma unroll
        for (int u = 0; u < 32; u++) s += W[j * 32 + u] * y[u];
        out[j] = s;
    }
}

// ---------------------------------------------------------------------------
// Phase D: 3 real serial S-LSTM blocks (1 wave each) + heater blocks.
// Lane k owns hidden unit k (k<40); 160 Whh floats/lane. Unroll x8, prefetch
// depth 8, 2-way partial accumulators, masked tail steps.
// ---------------------------------------------------------------------------
__global__ void __attribute__((amdgpu_flat_work_group_size(64, 64), amdgpu_waves_per_eu(1, 1)))
s_lstm(const float* __restrict__ Gs, const int* __restrict__ meta,
       const float* __restrict__ pWhh, const float* __restrict__ cWhh, const float* __restrict__ sWhh,
       float* __restrict__ H, int* __restrict__ flag) {
    if (blockIdx.x >= 3) {
        heater_spin(flag, 3, (float*)(flag + 4));
        return;
    }
    int l = blockIdx.x;
    const float* Whh = (l == 0) ? pWhh : (l == 1) ? cWhh : sWhh;
    int count = meta[l];
    int base = meta[3 + l];
    int k = threadIdx.x;
    int kk = (k < 40) ? k : 0;
    float Wi[40], Wf[40], Wg[40], Wo[40];
    #pragma unroll
    for (int j = 0; j < 40; j++) {
        Wi[j] = Whh[kk * 40 + j];
        Wf[j] = Whh[(40 + kk) * 40 + j];
        Wg[j] = Whh[(80 + kk) * 40 + j];
        Wo[j] = Whh[(120 + kk) * 40 + j];
    }
    float h = 0.f, c = 0.f;
    const float* G = Gs + (size_t)base * 160 + kk;
    float pi[8], pf[8], pg[8], po[8];
    #pragma unroll
    for (int u = 0; u < 8; u++) {
        const float* g0 = G + u * 160;
        pi[u] = g0[0]; pf[u] = g0[40]; pg[u] = g0[80]; po[u] = g0[120];
    }
    int steps = (count + 7) & ~7;
    for (int t = 0; t < steps; t += 8) {
        #pragma unroll
        for (int u = 0; u < 8; u++) {
            float gi = pi[u], gf = pf[u], gg = pg[u], go = po[u];
            const float* gn = G + (t + u + 8) * 160;   // overrun stays inside d_ws
            pi[u] = gn[0]; pf[u] = gn[40]; pg[u] = gn[80]; po[u] = gn[120];
            float i0 = 0.f, i1 = 0.f, f0 = 0.f, f1 = 0.f;
            float g0 = 0.f, g1 = 0.f, o0 = 0.f, o1 = 0.f;
            #pragma unroll
            for (int j = 0; j < 40; j += 2) {
                float h0 = bcast_f(h, j);
                float h1 = bcast_f(h, j + 1);
                i0 = __builtin_fmaf(Wi[j],     h0, i0);
                f0 = __builtin_fmaf(Wf[j],     h0, f0);
                g0 = __builtin_fmaf(Wg[j],     h0, g0);
                o0 = __builtin_fmaf(Wo[j],     h0, o0);
                i1 = __builtin_fmaf(Wi[j + 1], h1, i1);
                f1 = __builtin_fmaf(Wf[j + 1], h1, f1);
                g1 = __builtin_fmaf(Wg[j + 1], h1, g1);
                o1 = __builtin_fmaf(Wo[j + 1], h1, o1);
            }
            gi += i0 + i1; gf += f0 + f1; gg += g0 + g1; go += o0 + o1;
            float iv = sigm(gi), fv = sigm(gf);
            float gv = 2.f * sigm(2.f * gg) - 1.f;     // tanh
            float ov = sigm(go);
            float cn = __builtin_fmaf(fv, c, iv * gv);
            float tc = 2.f * sigm(2.f * cn) - 1.f;     // tanh
            float hn = ov * tc;
            bool m = (t + u) < count;
            c = m ? cn : c;
            h = m ? hn : h;
        }
    }
    if (k < 40) H[l * 40 + k] = h;
    __syncthreads();
    if (k == 0) __hip_atomic_fetch_add(flag, 1, __ATOMIC_RELAXED, __HIP_MEMORY_SCOPE_AGENT);
}

// ---------------------------------------------------------------------------
// Phase E: fusion vector (216) + 16-unit ReLU MLP + scalar head.
// ---------------------------------------------------------------------------
__global__ void phaseE(const int* __restrict__ user, const int* __restrict__ nextitem,
                       const float* __restrict__ item_emb, const float* __restrict__ user_emb,
                       const float* __restrict__ ys, const float* __restrict__ H,
                       const float* __restrict__ W1, const float* __restrict__ b1,
                       const float* __restrict__ W2, const float* __restrict__ b2,
                       float* __restrict__ out) {
    __shared__ float f[216];
    __shared__ float hid[16];
    int tid = threadIdx.x;
    if (tid < 32)       f[tid] = item_emb[tid * 1000 + nextitem[0]];
    else if (tid < 64)  f[tid] = user_emb[(tid - 32) * 1000 + user[0]];
    else if (tid < 96)  f[tid] = ys[(size_t)(T - 1) * 32 + (tid - 64)];
    else if (tid < 136) f[tid] = H[2 * 40 + (tid - 96)];    // H_s
    else if (tid < 176) f[tid] = H[1 * 40 + (tid - 136)];   // H_c
    else if (tid < 216) f[tid] = H[0 * 40 + (tid - 176)];   // H_p
    __syncthreads();
    if (tid < 16) {
        float s = b1[tid];
        for (int u = 0; u < 216; u++) s += W1[tid * 216 + u] * f[u];
        hid[tid] = fmaxf(s, 0.f);
    }
    __syncthreads();
    if (tid == 0) {
        float s = b2[0];
        #pragma unroll
        for (int m = 0; m < 16; m++) s += W2[m] * hid[m];
        out[0] = s;
    }
}

extern "C" void kernel_launch(void* const* d_in, const int* in_sizes, int n_in,
                              void* d_out, int out_size, void* d_ws, size_t ws_size,
                              hipStream_t stream) {
    const int*   user      = (const int*)d_in[0];
    const int*   nextitem  = (const int*)d_in[1];
    const int*   seq_items = (const int*)d_in[2];
    const int*   seq_types = (const int*)d_in[3];
    const float* dwell     = (const float*)d_in[4];
    const float* item_emb  = (const float*)d_in[5];
    const float* user_emb  = (const float*)d_in[6];
    const float* click     = (const float*)d_in[7];
    const float* purch     = (const float*)d_in[8];
    const float* skip      = (const float*)d_in[9];
    const float* tWih = (const float*)d_in[10];
    const float* tWhh = (const float*)d_in[11];
    const float* tbih = (const float*)d_in[12];
    const float* tbhh = (const float*)d_in[13];
    const float* pWih = (const float*)d_in[14], *pWhh = (const float*)d_in[15];
    const float* pbih = (const float*)d_in[16], *pbhh = (const float*)d_in[17];
    const float* cWih = (const float*)d_in[18], *cWhh = (const float*)d_in[19];
    const float* cbih = (const float*)d_in[20], *cbhh = (const float*)d_in[21];
    const float* sWih = (const float*)d_in[22], *sWhh = (const float*)d_in[23];
    const float* sbih = (const float*)d_in[24], *sbhh = (const float*)d_in[25];
    const float* W1 = (const float*)d_in[26], *b1 = (const float*)d_in[27];
    const float* W2 = (const float*)d_in[28], *b2 = (const float*)d_in[29];

    float* ws  = (float*)d_ws;
    float* Gx  = ws;                        // T*128 floats
    float* ysb = Gx + (size_t)T * 128;      // T*32
    float* Gs  = ysb + (size_t)T * 32;      // T*160 (compacted)
    float* H   = Gs + (size_t)T * 160;      // 128 (120 used)
    int*   meta   = (int*)(H + 128);        // 8 (6 used)
    int*   rowidx = meta + 8;               // T
    int*   flags  = rowidx + T;             // 8 ints: [0]=time done, [1]=s count, [4..7]=dummy

    hipMemsetAsync(flags, 0, 32, stream);
    scan_types<<<1, 256, 0, stream>>>(seq_types, rowidx, meta);
    phaseA<<<T, 64, 0, stream>>>(seq_items, seq_types, dwell, item_emb, click, purch, skip,
                                 tWih, tbih, tbhh, Gx);
    time_lstm<<<257, 64, 0, stream>>>(Gx, tWhh, ysb, flags);
    phaseC<<<T, 64, 0, stream>>>(ysb, seq_types, rowidx,
                                 pWih, pbih, pbhh, cWih, cbih, cbhh, sWih, sbih, sbhh, Gs);
    s_lstm<<<256, 64, 0, stream>>>(Gs, meta, pWhh, cWhh, sWhh, H, flags + 1);
    phaseE<<<1, 256, 0, stream>>>(user, nextitem, item_emb, user_emb, ysb, H,
                                  W1, b1, W2, b2, (float*)d_out);
}

// Round 4
// 7472.738 us; speedup vs baseline: 1.9904x; 1.1328x over previous
//
#include <hip/hip_runtime.h>
#include <math.h>

#define T 16384

__device__ __forceinline__ float bcast_f(float v, int lane) {
    return __int_as_float(__builtin_amdgcn_readlane(__float_as_int(v), lane));
}
// sigm via v_exp + v_rcp (no precise-division sequence in the serial chain)
__device__ __forceinline__ float sigm(float x) {
    return __builtin_amdgcn_rcpf(1.0f + __builtin_amdgcn_exp2f(-1.4426950408889634f * x));
}

// ---------------------------------------------------------------------------
// Heater: keeps clocks boosted while a serial kernel runs. 4 waves/CU,
// ~1024 FMAs per flag poll (low fabric traffic). Exits when *flag >= target.
// ---------------------------------------------------------------------------
__device__ __forceinline__ void heater_spin(const int* flag, int target, float* dummy) {
    float a = threadIdx.x * 0.001f + 1.0001f;
    float b = 0.99991f;
    float c0 = 0.f, c1 = 1.f, c2 = 2.f, c3 = 3.f;
    for (;;) {
        #pragma unroll
        for (int i = 0; i < 256; i++) {
            c0 = __builtin_fmaf(a, b, c0);
            c1 = __builtin_fmaf(a, b, c1);
            c2 = __builtin_fmaf(a, b, c2);
            c3 = __builtin_fmaf(a, b, c3);
        }
        if (__hip_atomic_load(flag, __ATOMIC_RELAXED, __HIP_MEMORY_SCOPE_AGENT) >= target) break;
    }
    float s = (c0 + c1) + (c2 + c3);
    if (s == 1234.56789f) dummy[0] = s;  // unprovable: blocks DCE, never executes
}

// ---------------------------------------------------------------------------
// Scan: build compacted per-type row indices.
// List order: l0 = p (type==1), l1 = c (type==0), l2 = s (type==2)
// ---------------------------------------------------------------------------
__global__ void scan_types(const int* __restrict__ seq_types, int* __restrict__ rowidx,
                           int* __restrict__ meta) {
    __shared__ int cnt[256][3];
    __shared__ int pre[256][3];
    __shared__ int baseT[3];
    int tid = threadIdx.x;
    int c0 = 0, c1 = 0, c2 = 0;
    for (int u = 0; u < 64; u++) {
        int ty = seq_types[tid * 64 + u];
        c0 += (ty == 0); c1 += (ty == 1); c2 += (ty == 2);
    }
    cnt[tid][0] = c0; cnt[tid][1] = c1; cnt[tid][2] = c2;
    __syncthreads();
    if (tid == 0) {
        int s0 = 0, s1 = 0, s2 = 0;
        for (int i = 0; i < 256; i++) {
            pre[i][0] = s0; pre[i][1] = s1; pre[i][2] = s2;
            s0 += cnt[i][0]; s1 += cnt[i][1]; s2 += cnt[i][2];
        }
        int base_l0 = 0, base_l1 = s1, base_l2 = s1 + s0;
        baseT[1] = base_l0;  // p
        baseT[0] = base_l1;  // c
        baseT[2] = base_l2;  // s
        meta[0] = s1; meta[1] = s0; meta[2] = s2;
        meta[3] = base_l0; meta[4] = base_l1; meta[5] = base_l2;
    }
    __syncthreads();
    int r0 = pre[tid][0], r1 = pre[tid][1], r2 = pre[tid][2];
    for (int u = 0; u < 64; u++) {
        int t = tid * 64 + u;
        int ty = seq_types[t];
        int rank = (ty == 0) ? r0++ : (ty == 1) ? r1++ : r2++;
        rowidx[t] = baseT[ty] + rank;
    }
}

// ---------------------------------------------------------------------------
// Phase A: gather + typed projection + time-LSTM input gates.
// Gx layout: row t = 64 float2 pairs; pair L = (gate_row L, gate_row L+64).
// ---------------------------------------------------------------------------
__global__ void phaseA(const int* __restrict__ seq_items, const int* __restrict__ seq_types,
                       const float* __restrict__ dwell, const float* __restrict__ item_emb,
                       const float* __restrict__ click_proj, const float* __restrict__ purchase_proj,
                       const float* __restrict__ skip_proj, const float* __restrict__ Wih,
                       const float* __restrict__ bih, const float* __restrict__ bhh,
                       float* __restrict__ Gx) {
    int t = blockIdx.x;
    int lane = threadIdx.x;
    __shared__ float e[32];
    __shared__ float xs[10];
    int item = seq_items[t];
    if (lane < 32) e[lane] = item_emb[lane * 1000 + item];
    if (lane == 32) xs[0] = dwell[t];
    __syncthreads();
    int ty = seq_types[t];
    const float* P = (ty == 0) ? click_proj : (ty == 1) ? purchase_proj : skip_proj;
    if (lane < 9) {
        float s = 0.f;
        #pragma unroll
        for (int j = 0; j < 32; j++) s += P[lane * 32 + j] * e[j];
        xs[1 + lane] = s;
    }
    __syncthreads();
    int g1 = lane, g2 = lane + 64;
    float s1 = bih[g1] + bhh[g1];
    float s2 = bih[g2] + bhh[g2];
    #pragma unroll
    for (int u = 0; u < 10; u++) {
        s1 += Wih[g1 * 10 + u] * xs[u];
        s2 += Wih[g2 * 10 + u] * xs[u];
    }
    float2 v; v.x = s1; v.y = s2;
    ((float2*)(Gx + (size_t)t * 128))[lane] = v;
}

// ---------------------------------------------------------------------------
// Phase B: serial time-LSTM, 1 real wave (block 0) + heaters.
// Gate-split: lane L owns rows L and L+64. ys buffered in LDS, flushed /128.
// ---------------------------------------------------------------------------
__global__ void __attribute__((amdgpu_flat_work_group_size(64, 64), amdgpu_waves_per_eu(1, 1)))
time_lstm(const float* __restrict__ Gx, const float* __restrict__ Whh, float* __restrict__ ys,
          int* __restrict__ flag) {
    if (blockIdx.x != 0) {
        heater_spin(flag, 1, (float*)(flag + 4));
        return;
    }
    int L = threadIdx.x;
    bool isLow = (L < 32);
    int unit = L & 31;
    float WA[32], WB[32];
    #pragma unroll
    for (int j = 0; j < 32; j++) {
        WA[j] = Whh[L * 32 + j];
        WB[j] = Whh[(L + 64) * 32 + j];
    }
    __shared__ float ysbuf[128 * 32];   // 16 KB
    int paddr = (L ^ 32) << 2;
    float mB = isLow ? 2.0f : 1.0f;     // tanh(x) = 2*sigm(2x)-1 on low lanes
    float c = 0.f, h = 0.f;
    const float2* G2 = (const float2*)Gx;   // row t at G2[t*64 + L]
    float2 pr[8];
    #pragma unroll
    for (int u = 0; u < 8; u++) pr[u] = G2[u * 64 + L];
    for (int tc = 0; tc < T; tc += 128) {
        for (int tt = 0; tt < 128; tt += 8) {
            #pragma unroll
            for (int u = 0; u < 8; u++) {
                int s = tt + u;                       // local step in chunk
                float gxA = pr[u].x, gxB = pr[u].y;
                pr[u] = G2[(size_t)(tc + s + 8) * 64 + L];   // overrun lands in ys region
                float a0 = 0.f, a1 = 0.f, a2 = 0.f, a3 = 0.f;
                float b0 = 0.f, b1 = 0.f, b2 = 0.f, b3 = 0.f;
                #pragma unroll
                for (int j = 0; j < 32; j += 4) {
                    float h0 = bcast_f(h, j);
                    float h1 = bcast_f(h, j + 1);
                    float h2 = bcast_f(h, j + 2);
                    float h3 = bcast_f(h, j + 3);
                    a0 = __builtin_fmaf(WA[j],     h0, a0);
                    b0 = __builtin_fmaf(WB[j],     h0, b0);
                    a1 = __builtin_fmaf(WA[j + 1], h1, a1);
                    b1 = __builtin_fmaf(WB[j + 1], h1, b1);
                    a2 = __builtin_fmaf(WA[j + 2], h2, a2);
                    b2 = __builtin_fmaf(WB[j + 2], h2, b2);
                    a3 = __builtin_fmaf(WA[j + 3], h3, a3);
                    b3 = __builtin_fmaf(WB[j + 3], h3, b3);
                }
                float gA = ((a0 + a1) + (a2 + a3)) + gxA;
                float gB = ((b0 + b1) + (b2 + b3)) + gxB;
                float v1 = sigm(gA);                           // i (low) / f (high)
                float u2 = sigm(gB * mB);
                float v2 = isLow ? 2.f * u2 - 1.f : u2;        // g (low) / o (high)
                float p  = v1 * v2;                            // i*g on low
                float x1 = __int_as_float(__builtin_amdgcn_ds_bpermute(
                               paddr, __float_as_int(isLow ? p : v1)));
                float x2 = __int_as_float(__builtin_amdgcn_ds_bpermute(
                               paddr, __float_as_int(v2)));
                float fv = isLow ? x1 : v1;
                float pv = isLow ? p  : x1;
                float ov = isLow ? x2 : v2;
                c = __builtin_fmaf(fv, c, pv);
                float tc2 = 2.f * sigm(2.f * c) - 1.f;         // tanh(c)
                h = ov * tc2;
                if (isLow) ysbuf[s * 32 + unit] = h;
            }
        }
        // bulk flush 128 steps of ys (single wave: no barrier needed)
        const float4* src = (const float4*)ysbuf;
        float4* dst = (float4*)(ys + (size_t)tc * 32);
        #pragma unroll
        for (int i = 0; i < 16; i++) dst[i * 64 + L] = src[i * 64 + L];
    }
    if (L == 0) __hip_atomic_store(flag, 1, __ATOMIC_RELAXED, __HIP_MEMORY_SCOPE_AGENT);
}

// ---------------------------------------------------------------------------
// Phase C: S-LSTM input gates, compacted by type, interleaved per unit:
// Gs row r = 40 float4s; float4 k = (i_k, f_k, g_k, o_k) pre-activations.
// ---------------------------------------------------------------------------
__global__ void phaseC(const float* __restrict__ ys, const int* __restrict__ seq_types,
                       const int* __restrict__ rowidx,
                       const float* __restrict__ pW, const float* __restrict__ pbi, const float* __restrict__ pbh,
                       const float* __restrict__ cW, const float* __restrict__ cbi, const float* __restrict__ cbh,
                       const float* __restrict__ sW, const float* __restrict__ sbi, const float* __restrict__ sbh,
                       float* __restrict__ Gs) {
    int t = blockIdx.x;
    int lane = threadIdx.x;
    __shared__ float y[32];
    if (lane < 32) y[lane] = ys[t * 32 + lane];
    __syncthreads();
    int ty = seq_types[t];
    const float* W; const float* bi; const float* bh;
    if (ty == 1)      { W = pW; bi = pbi; bh = pbh; }
    else if (ty == 0) { W = cW; bi = cbi; bh = cbh; }
    else              { W = sW; bi = sbi; bh = sbh; }
    float* out = Gs + (size_t)rowidx[t] * 160;
    for (int j = lane; j < 160; j += 64) {
        float s = bi[j] + bh[j];
        #pragma unroll
        for (int u = 0; u < 32; u++) s += W[j * 32 + u] * y[u];
        out[(j % 40) * 4 + (j / 40)] = s;     // interleave: unit-major float4
    }
}

// ---------------------------------------------------------------------------
// Phase D: 3 serial S-LSTMs over compacted lists (1 wave each) + heaters.
// Lane k owns unit k (k<40); one dwordx4 gate load per step, prefetch 8.
// ---------------------------------------------------------------------------
__global__ void __attribute__((amdgpu_flat_work_group_size(64, 64), amdgpu_waves_per_eu(1, 1)))
s_lstm(const float* __restrict__ Gs, const int* __restrict__ meta,
       const float* __restrict__ pWhh, const float* __restrict__ cWhh, const float* __restrict__ sWhh,
       float* __restrict__ H, int* __restrict__ flag) {
    if (blockIdx.x >= 3) {
        heater_spin(flag, 3, (float*)(flag + 4));
        return;
    }
    int l = blockIdx.x;
    const float* Whh = (l == 0) ? pWhh : (l == 1) ? cWhh : sWhh;
    int count = meta[l];
    int base = meta[3 + l];
    int k = threadIdx.x;
    int kk = (k < 40) ? k : 0;
    float Wi[40], Wf[40], Wg[40], Wo[40];
    #pragma unroll
    for (int j = 0; j < 40; j++) {
        Wi[j] = Whh[kk * 40 + j];
        Wf[j] = Whh[(40 + kk) * 40 + j];
        Wg[j] = Whh[(80 + kk) * 40 + j];
        Wo[j] = Whh[(120 + kk) * 40 + j];
    }
    float h = 0.f, c = 0.f;
    const float4* G4 = (const float4*)(Gs + (size_t)base * 160);
    float4 pr[8];
    #pragma unroll
    for (int u = 0; u < 8; u++) pr[u] = G4[u * 40 + kk];
    int steps = (count + 7) & ~7;
    for (int t = 0; t < steps; t += 8) {
        #pragma unroll
        for (int u = 0; u < 8; u++) {
            float4 g = pr[u];
            pr[u] = G4[(size_t)(t + u + 8) * 40 + kk];   // overrun stays inside d_ws
            float i0 = 0.f, i1 = 0.f, f0 = 0.f, f1 = 0.f;
            float g0 = 0.f, g1 = 0.f, o0 = 0.f, o1 = 0.f;
            #pragma unroll
            for (int j = 0; j < 40; j += 2) {
                float h0 = bcast_f(h, j);
                float h1 = bcast_f(h, j + 1);
                i0 = __builtin_fmaf(Wi[j],     h0, i0);
                f0 = __builtin_fmaf(Wf[j],     h0, f0);
                g0 = __builtin_fmaf(Wg[j],     h0, g0);
                o0 = __builtin_fmaf(Wo[j],     h0, o0);
                i1 = __builtin_fmaf(Wi[j + 1], h1, i1);
                f1 = __builtin_fmaf(Wf[j + 1], h1, f1);
                g1 = __builtin_fmaf(Wg[j + 1], h1, g1);
                o1 = __builtin_fmaf(Wo[j + 1], h1, o1);
            }
            float gi = g.x + i0 + i1, gf = g.y + f0 + f1;
            float gg = g.z + g0 + g1, go = g.w + o0 + o1;
            float iv = sigm(gi), fv = sigm(gf);
            float gv = 2.f * sigm(2.f * gg) - 1.f;     // tanh
            float ov = sigm(go);
            float cn = __builtin_fmaf(fv, c, iv * gv);
            float tcv = 2.f * sigm(2.f * cn) - 1.f;    // tanh
            float hn = ov * tcv;
            bool m = (t + u) < count;
            c = m ? cn : c;
            h = m ? hn : h;
        }
    }
    if (k < 40) H[l * 40 + k] = h;
    __syncthreads();
    if (k == 0) __hip_atomic_fetch_add(flag, 1, __ATOMIC_RELAXED, __HIP_MEMORY_SCOPE_AGENT);
}

// ---------------------------------------------------------------------------
// Phase E: fusion vector (216) + 16-unit ReLU MLP + scalar head.
// ---------------------------------------------------------------------------
__global__ void phaseE(const int* __restrict__ user, const int* __restrict__ nextitem,
                       const float* __restrict__ item_emb, const float* __restrict__ user_emb,
                       const float* __restrict__ ys, const float* __restrict__ H,
                       const float* __restrict__ W1, const float* __restrict__ b1,
                       const float* __restrict__ W2, const float* __restrict__ b2,
                       float* __restrict__ out) {
    __shared__ float f[216];
    __shared__ float hid[16];
    int tid = threadIdx.x;
    if (tid < 32)       f[tid] = item_emb[tid * 1000 + nextitem[0]];
    else if (tid < 64)  f[tid] = user_emb[(tid - 32) * 1000 + user[0]];
    else if (tid < 96)  f[tid] = ys[(size_t)(T - 1) * 32 + (tid - 64)];
    else if (tid < 136) f[tid] = H[2 * 40 + (tid - 96)];    // H_s
    else if (tid < 176) f[tid] = H[1 * 40 + (tid - 136)];   // H_c
    else if (tid < 216) f[tid] = H[0 * 40 + (tid - 176)];   // H_p
    __syncthreads();
    if (tid < 16) {
        float s = b1[tid];
        for (int u = 0; u < 216; u++) s += W1[tid * 216 + u] * f[u];
        hid[tid] = fmaxf(s, 0.f);
    }
    __syncthreads();
    if (tid == 0) {
        float s = b2[0];
        #pragma unroll
        for (int m = 0; m < 16; m++) s += W2[m] * hid[m];
        out[0] = s;
    }
}

extern "C" void kernel_launch(void* const* d_in, const int* in_sizes, int n_in,
                              void* d_out, int out_size, void* d_ws, size_t ws_size,
                              hipStream_t stream) {
    const int*   user      = (const int*)d_in[0];
    const int*   nextitem  = (const int*)d_in[1];
    const int*   seq_items = (const int*)d_in[2];
    const int*   seq_types = (const int*)d_in[3];
    const float* dwell     = (const float*)d_in[4];
    const float* item_emb  = (const float*)d_in[5];
    const float* user_emb  = (const float*)d_in[6];
    const float* click     = (const float*)d_in[7];
    const float* purch     = (const float*)d_in[8];
    const float* skip      = (const float*)d_in[9];
    const float* tWih = (const float*)d_in[10];
    const float* tWhh = (const float*)d_in[11];
    const float* tbih = (const float*)d_in[12];
    const float* tbhh = (const float*)d_in[13];
    const float* pWih = (const float*)d_in[14], *pWhh = (const float*)d_in[15];
    const float* pbih = (const float*)d_in[16], *pbhh = (const float*)d_in[17];
    const float* cWih = (const float*)d_in[18], *cWhh = (const float*)d_in[19];
    const float* cbih = (const float*)d_in[20], *cbhh = (const float*)d_in[21];
    const float* sWih = (const float*)d_in[22], *sWhh = (const float*)d_in[23];
    const float* sbih = (const float*)d_in[24], *sbhh = (const float*)d_in[25];
    const float* W1 = (const float*)d_in[26], *b1 = (const float*)d_in[27];
    const float* W2 = (const float*)d_in[28], *b2 = (const float*)d_in[29];

    float* ws  = (float*)d_ws;
    float* Gx  = ws;                        // T*128 floats (interleaved pairs)
    float* ysb = Gx + (size_t)T * 128;      // T*32
    float* Gs  = ysb + (size_t)T * 32;      // T*160 (compacted, float4/unit)
    float* H   = Gs + (size_t)T * 160;      // 128 (120 used)
    int*   meta   = (int*)(H + 128);        // 8 (6 used)
    int*   rowidx = meta + 8;               // T
    int*   flags  = rowidx + T;             // 8 ints

    hipMemsetAsync(flags, 0, 32, stream);
    scan_types<<<1, 256, 0, stream>>>(seq_types, rowidx, meta);
    phaseA<<<T, 64, 0, stream>>>(seq_items, seq_types, dwell, item_emb, click, purch, skip,
                                 tWih, tbih, tbhh, Gx);
    time_lstm<<<1024, 64, 0, stream>>>(Gx, tWhh, ysb, flags);
    phaseC<<<T, 64, 0, stream>>>(ysb, seq_types, rowidx,
                                 pWih, pbih, pbhh, cWih, cbih, cbhh, sWih, sbih, sbhh, Gs);
    s_lstm<<<1024, 64, 0, stream>>>(Gs, meta, pWhh, cWhh, sWhh, H, flags + 1);
    phaseE<<<1, 256, 0, stream>>>(user, nextitem, item_emb, user_emb, ysb, H,
                                  W1, b1, W2, b2, (float*)d_out);
}